// Round 10
// baseline (757.048 us; speedup 1.0000x reference)
//
#include <hip/hip_runtime.h>

#define NGRAPH 1000
#define P      100
#define EPG    1200
#define INF    16
#define HID    64
#define NOUT   5

#define ASTR   68    // A row stride (17 granules, odd -> conflict-free mm reads)
#define TSTR   8     // T1/T2 row stride = slice width
#define NPAD   112   // mm covers 8 groups * 13 = 104 rows; rows 100.. = don't-care

// LDS: A 112*68*4=30464 + T1/T2 2*112*8*4=7168 + csr_src 2400 + csr_off 404
//      + sdinv 400 = 40,836 B -> 4 blocks/CU (4 x 40960 = 160 KiB exactly).
//
// HARD RULES (r6/r7/r9 lessons):
//  - every loop touching acc[] is #pragma unroll, compile-time trip, no guards
//  - acc[] must NOT be live through gather code in the same wave's path ->
//    producer/consumer wave split: waves 0-1 matmul-only, waves 2-3 gather-only
//  - amdgpu_waves_per_eu(4,4): LDS caps us at 4 waves/EU anyway; telling the
//    allocator stops it spilling to chase 8 waves/EU (r9: it picked 64 VGPR
//    and spilled 1.9 GB instead of using the 128 the occupancy allows)

__device__ __forceinline__ void fma4(float4& a, float s, const float4 w) {
    a.x += s * w.x; a.y += s * w.y; a.z += s * w.z; a.w += s * w.w;
}

// All-thread gather (layer prologue only): q-split, 2-way edge unroll.
__device__ __forceinline__ void prop8q(
    const float* __restrict__ S, int sstride, int soff,
    float* __restrict__ D,
    const unsigned short* __restrict__ csr_src,
    const int* __restrict__ csr_off,
    const float* __restrict__ sdinv,
    int tid)
{
    const int q = tid & 1;
    const int n = tid >> 1;
    if (n < P) {
        const int kb = csr_off[n], ke = csr_off[n + 1];
        float ax = 0.f, ay = 0.f, az = 0.f, aw = 0.f;
        float bx = 0.f, by = 0.f, bz = 0.f, bw = 0.f;
        int k = kb;
        for (; k + 1 < ke; k += 2) {
            int s0 = csr_src[k], s1 = csr_src[k + 1];
            float w0 = sdinv[s0], w1 = sdinv[s1];
            const float4 x0 = *(const float4*)&S[s0 * sstride + soff + q * 4];
            const float4 x1 = *(const float4*)&S[s1 * sstride + soff + q * 4];
            ax += w0 * x0.x; ay += w0 * x0.y; az += w0 * x0.z; aw += w0 * x0.w;
            bx += w1 * x1.x; by += w1 * x1.y; bz += w1 * x1.z; bw += w1 * x1.w;
        }
        if (k < ke) {
            int s0 = csr_src[k];
            float w0 = sdinv[s0];
            const float4 x0 = *(const float4*)&S[s0 * sstride + soff + q * 4];
            ax += w0 * x0.x; ay += w0 * x0.y; az += w0 * x0.z; aw += w0 * x0.w;
        }
        float m = -sdinv[n];
        float4 o;
        o.x = m * (ax + bx); o.y = m * (ay + by);
        o.z = m * (az + bz); o.w = m * (aw + bw);
        *(float4*)&D[n * TSTR + q * 4] = o;
    }
}

// Gather-wave prop: one node per thread (t=0..127), all 8 slice cols.
// isX2=0: D = -dinv[n]*sum dinv[s]*S[s];  isX2=1: D = -2*dinv[n]*sum... - A0.
__device__ __forceinline__ void prop8g(
    const float* __restrict__ S, int sstride, int soff,
    float* __restrict__ D,
    const float* __restrict__ A0, int aoff, int isX2,
    const unsigned short* __restrict__ csr_src,
    const int* __restrict__ csr_off,
    const float* __restrict__ sdinv,
    int t)
{
    if (t < P) {
        const int kb = csr_off[t], ke = csr_off[t + 1];
        float4 aA = {0,0,0,0}, aB = {0,0,0,0};
        float4 bA = {0,0,0,0}, bB = {0,0,0,0};
        int k = kb;
        for (; k + 1 < ke; k += 2) {
            int s0 = csr_src[k], s1 = csr_src[k + 1];
            float w0 = sdinv[s0], w1 = sdinv[s1];
            const float* p0 = &S[s0 * sstride + soff];
            const float* p1 = &S[s1 * sstride + soff];
            const float4 x0A = *(const float4*)p0, x0B = *(const float4*)(p0 + 4);
            const float4 x1A = *(const float4*)p1, x1B = *(const float4*)(p1 + 4);
            fma4(aA, w0, x0A); fma4(aB, w0, x0B);
            fma4(bA, w1, x1A); fma4(bB, w1, x1B);
        }
        if (k < ke) {
            int s0 = csr_src[k];
            float w0 = sdinv[s0];
            const float* p0 = &S[s0 * sstride + soff];
            fma4(aA, w0, *(const float4*)p0);
            fma4(aB, w0, *(const float4*)(p0 + 4));
        }
        aA.x += bA.x; aA.y += bA.y; aA.z += bA.z; aA.w += bA.w;
        aB.x += bB.x; aB.y += bB.y; aB.z += bB.z; aB.w += bB.w;
        float4 oA, oB;
        if (!isX2) {
            float m = -sdinv[t];
            oA.x = m * aA.x; oA.y = m * aA.y; oA.z = m * aA.z; oA.w = m * aA.w;
            oB.x = m * aB.x; oB.y = m * aB.y; oB.z = m * aB.z; oB.w = m * aB.w;
        } else {
            float m = -2.f * sdinv[t];
            const float* p = &A0[t * ASTR + aoff];
            const float4 zA = *(const float4*)p, zB = *(const float4*)(p + 4);
            oA.x = m * aA.x - zA.x; oA.y = m * aA.y - zA.y;
            oA.z = m * aA.z - zA.z; oA.w = m * aA.w - zA.w;
            oB.x = m * aB.x - zB.x; oB.y = m * aB.y - zB.y;
            oB.z = m * aB.z - zB.z; oB.w = m * aB.w - zB.w;
        }
        *(float4*)&D[t * TSTR]     = oA;
        *(float4*)&D[t * TSTR + 4] = oB;
    }
}

// mm section: acc += X[n0..n0+12][8 feats] @ W-rows. All compile-time unrolled.
__device__ __forceinline__ void mm_sec(
    const float* __restrict__ xp, int xstr, int xoff,
    const float* __restrict__ W, int wrow0,
    int cq4, int n0, float4 (&acc)[13])
{
    for (int j4 = 0; j4 < 8; j4 += 4) {
        const float4 w0 = *(const float4*)&W[(wrow0 + j4 + 0) * HID + cq4];
        const float4 w1 = *(const float4*)&W[(wrow0 + j4 + 1) * HID + cq4];
        const float4 w2 = *(const float4*)&W[(wrow0 + j4 + 2) * HID + cq4];
        const float4 w3 = *(const float4*)&W[(wrow0 + j4 + 3) * HID + cq4];
        const float* xb = xp + n0 * xstr + xoff + j4;
#pragma unroll
        for (int i = 0; i < 13; i++) {
            const float4 x = *(const float4*)&xb[i * xstr];
            fma4(acc[i], x.x, w0); fma4(acc[i], x.y, w1);
            fma4(acc[i], x.z, w2); fma4(acc[i], x.w, w3);
        }
    }
}

template <int F>
__device__ __forceinline__ void cheb_layer(
    float* __restrict__ A, float* __restrict__ T1, float* __restrict__ T2,
    const unsigned short* __restrict__ csr_src,
    const int* __restrict__ csr_off,
    const float* __restrict__ sdinv,
    const float* __restrict__ W, const float* __restrict__ bias,
    int tid)
{
    // prologue: X1-gather slice 0 (all threads)
    prop8q(A, ASTR, 0, T1, csr_src, csr_off, sdinv, tid);
    __syncthreads();

    // mm-wave tile: 4 cols x 13 rows (tid<128); gather-wave node: tid-128
    const int cq4 = (tid & 15) * 4;
    const int n0  = (tid >> 4) * 13;      // meaningful only for tid<128 (<=103)
    const int gt  = tid - 128;

    float4 acc[13];
    const float4 bv = *(const float4*)&bias[cq4];
#pragma unroll
    for (int i = 0; i < 13; i++) acc[i] = bv;

    for (int cb = 0; cb < F; cb += 8) {
        // phase B: mm sec0(A)+sec1(T1)  ||  gather X2g(cb) -> T2
        if (tid < 128) {
            mm_sec(A,  ASTR, cb, W, cb,     cq4, n0, acc);
            mm_sec(T1, TSTR, 0,  W, F + cb, cq4, n0, acc);
        } else {
            prop8g(T1, TSTR, 0, T2, A, cb, 1, csr_src, csr_off, sdinv, gt);
        }
        __syncthreads();
        // phase C: mm sec2(T2)  ||  gather X1g(cb+8) -> T1
        if (tid < 128) {
            mm_sec(T2, TSTR, 0, W, 2 * F + cb, cq4, n0, acc);
        } else if (cb + 8 < F) {
            prop8g(A, ASTR, cb + 8, T1, (const float*)0, 0, 0,
                   csr_src, csr_off, sdinv, gt);
        }
        __syncthreads();
    }

    // H = relu(acc) -> A rows n0..n0+12 (pad rows 100..103 don't-care)
    if (tid < 128) {
#pragma unroll
        for (int i = 0; i < 13; i++) {
            float4 o;
            o.x = fmaxf(acc[i].x, 0.f); o.y = fmaxf(acc[i].y, 0.f);
            o.z = fmaxf(acc[i].z, 0.f); o.w = fmaxf(acc[i].w, 0.f);
            *(float4*)&A[(n0 + i) * ASTR + cq4] = o;
        }
    }
    __syncthreads();
}

__global__ __launch_bounds__(256)
__attribute__((amdgpu_waves_per_eu(4, 4)))
void gnn_kernel(
    const float* __restrict__ feat,
    const int* __restrict__ src, const int* __restrict__ dst,
    const float* __restrict__ W1, const float* __restrict__ b1,
    const float* __restrict__ W2, const float* __restrict__ b2,
    const float* __restrict__ W3, const float* __restrict__ b3,
    const float* __restrict__ Wfc, const float* __restrict__ bfc,
    float* __restrict__ out)
{
    __shared__ __align__(16) float A[NPAD * ASTR];
    __shared__ __align__(16) float T1[NPAD * TSTR];
    __shared__ __align__(16) float T2[NPAD * TSTR];
    __shared__ unsigned short csr_src[EPG];
    __shared__ int   csr_off[P + 1];
    __shared__ float sdinv[P];

    const int g = blockIdx.x;
    const int tid = threadIdx.x;
    const int base = g * P;
    const int* srcg = src + g * EPG;
    const int* dstg = dst + g * EPG;

    int* deg = (int*)T1;   // aliased; consumed before layer 1
    int* cur = (int*)T2;   // aliased; consumed before layer 1

    // ---- degree count + feat load ----
    for (int i = tid; i < P; i += 256) deg[i] = 0;
    __syncthreads();
    for (int e = tid; e < EPG; e += 256) {
        int d = dstg[e] - base;
        atomicAdd(&deg[d], 1);
    }
    for (int i = tid; i < P * INF / 4; i += 256) {
        int n = i >> 2, fq = (i & 3) * 4;
        *(float4*)&A[n * ASTR + fq] = *(const float4*)&feat[(size_t)base * INF + i * 4];
    }
    __syncthreads();

    for (int i = tid; i < P; i += 256) {
        int dg = deg[i] > 1 ? deg[i] : 1;
        sdinv[i] = rsqrtf((float)dg);
    }
    // ---- prefix scan of degrees: serial by thread 0 (P=100, negligible) ----
    if (tid == 0) {
        int run = 0;
        csr_off[0] = 0;
        for (int i = 0; i < P; i++) { run += deg[i]; csr_off[i + 1] = run; }
    }
    __syncthreads();
    for (int i = tid; i < P; i += 256) cur[i] = csr_off[i];
    __syncthreads();
    // ---- CSR fill ----
    for (int e = tid; e < EPG; e += 256) {
        int s = srcg[e] - base;
        int d = dstg[e] - base;
        int pos = atomicAdd(&cur[d], 1);
        csr_src[pos] = (unsigned short)s;
    }
    __syncthreads();

    // ---- 3 ChebConv layers ----
    cheb_layer<INF>(A, T1, T2, csr_src, csr_off, sdinv, W1, b1, tid);
    cheb_layer<HID>(A, T1, T2, csr_src, csr_off, sdinv, W2, b2, tid);
    cheb_layer<HID>(A, T1, T2, csr_src, csr_off, sdinv, W3, b3, tid);

    // ---- mean pool + FC (T1 as scratch: 320 floats <= 896) ----
    {
        const int lane = tid & 63, w = tid >> 6;
        float s = 0.f;
        for (int n = w; n < P; n += 4) s += A[n * ASTR + lane];
        T1[w * 64 + lane] = s;
    }
    __syncthreads();
    if (tid < HID) {
        float hg = (T1[tid] + T1[64 + tid] + T1[128 + tid] + T1[192 + tid]) * (1.0f / P);
        T1[256 + tid] = hg;
    }
    __syncthreads();
    if (tid < NOUT) {
        float o = bfc[tid];
        for (int c = 0; c < HID; c++) o += T1[256 + c] * Wfc[c * NOUT + tid];
        out[g * NOUT + tid] = o;
    }
}

extern "C" void kernel_launch(void* const* d_in, const int* in_sizes, int n_in,
                              void* d_out, int out_size, void* d_ws, size_t ws_size,
                              hipStream_t stream)
{
    const float* feat = (const float*)d_in[0];
    const int*   src  = (const int*)d_in[1];
    const int*   dst  = (const int*)d_in[2];
    const float* W1  = (const float*)d_in[5];
    const float* b1  = (const float*)d_in[6];
    const float* W2  = (const float*)d_in[7];
    const float* b2  = (const float*)d_in[8];
    const float* W3  = (const float*)d_in[9];
    const float* b3  = (const float*)d_in[10];
    const float* Wfc = (const float*)d_in[11];
    const float* bfc = (const float*)d_in[12];
    float* out = (float*)d_out;

    gnn_kernel<<<NGRAPH, 256, 0, stream>>>(feat, src, dst,
                                           W1, b1, W2, b2, W3, b3, Wfc, bfc, out);
}

// Round 11
// 277.499 us; speedup vs baseline: 2.7281x; 2.7281x over previous
//
#include <hip/hip_runtime.h>

#define NGRAPH 1000
#define P      100
#define EPG    1200
#define INF    16
#define HID    64
#define NOUT   5

#define ASTR   68    // A row stride (17 granules, odd -> conflict-free matmul reads)
#define TSTR   8     // T1/T2 row stride = slice width
#define NPAD   112   // 16 uniform groups * 7 nodes (rows 100..111 = don't-care pad)

// LDS: A 112*68*4=30464 + T1/T2 2*112*8*4=7168 + csr_src 2400 + csr_off 404
//      + sdinv 400 = 40,836 B -> 4 blocks/CU.  deg/cursor alias T1/T2.
//
// HARD RULES (r6/r7/r9/r10 lessons):
//  - every loop touching acc[] is #pragma unroll, compile-time trip, no guards
//  - the allocator pins this kernel at 64 VGPRs (8 waves/EU target) and
//    SPILLS anything above it — amdgpu_waves_per_eu(4,4) did NOT move it
//    (r10: VGPR stayed 64, 1.7 GB scratch). Keep peak pressure < 64:
//    acc[7] (28) + gather temps (~20) + addressing (~10) is the budget.
//  - r8 3-phase structure (gather / gather / matmul, uniform barriers) is the
//    verified-clean baseline; this round changes ONLY the gather inner loop:
//    2-way edge unroll with a SINGLE accumulator set (two ds_read_b128 chains
//    in flight, +7 regs — not r9's two-accumulator variant, +20 regs).

__device__ __forceinline__ void fma4(float4& a, float s, const float4 w) {
    a.x += s * w.x; a.y += s * w.y; a.z += s * w.z; a.w += s * w.w;
}

// Gather one 8-column slice D[n][0..8) (n < P) from CSR.
// isX2=0: D = -dinv[n] * sum_e dinv[s]*S[s]            (X1 = -Ax(X0))
// isX2=1: D = -2*dinv[n]*sum_e dinv[s]*S[s] - A0[n]    (X2 = -2Ax(X1) - X0)
__device__ __forceinline__ void prop8(
    const float* __restrict__ S, int sstride, int soff,
    float* __restrict__ D,
    const float* __restrict__ A0, int aoff, int isX2,
    const unsigned short* __restrict__ csr_src,
    const int* __restrict__ csr_off,
    const float* __restrict__ sdinv,
    int tid)
{
    const int q = tid & 1;        // feature quad within slice
    const int n = tid >> 1;       // node (128 slots >= 100)
    if (n < P) {
        const int kb = csr_off[n], ke = csr_off[n + 1];
        float ax = 0.f, ay = 0.f, az = 0.f, aw = 0.f;
        int k = kb;
        // 2-way unrolled: both b128 loads issue before either FMA chain
        for (; k + 1 < ke; k += 2) {
            int s0 = csr_src[k];
            int s1 = csr_src[k + 1];
            float w0 = sdinv[s0];
            float w1 = sdinv[s1];
            const float4 x0 = *(const float4*)&S[s0 * sstride + soff + q * 4];
            const float4 x1 = *(const float4*)&S[s1 * sstride + soff + q * 4];
            ax += w0 * x0.x; ay += w0 * x0.y; az += w0 * x0.z; aw += w0 * x0.w;
            ax += w1 * x1.x; ay += w1 * x1.y; az += w1 * x1.z; aw += w1 * x1.w;
        }
        if (k < ke) {
            int s0 = csr_src[k];
            float w0 = sdinv[s0];
            const float4 x0 = *(const float4*)&S[s0 * sstride + soff + q * 4];
            ax += w0 * x0.x; ay += w0 * x0.y; az += w0 * x0.z; aw += w0 * x0.w;
        }
        float dn = sdinv[n];
        float4 o;
        if (!isX2) {
            float m = -dn;
            o.x = m * ax; o.y = m * ay; o.z = m * az; o.w = m * aw;
        } else {
            float m = -2.f * dn;
            const float4 x0 = *(const float4*)&A0[n * ASTR + aoff + q * 4];
            o.x = m * ax - x0.x; o.y = m * ay - x0.y;
            o.z = m * az - x0.z; o.w = m * aw - x0.w;
        }
        *(float4*)&D[n * TSTR + q * 4] = o;
    }
}

// One ChebConv(K=3) layer: A (F cols) -> relu([X0|X1|X2]@W + b) -> A.
// Thread: cq4=(tid&15)*4 output cols; 7 uniform nodes n0=(tid>>4)*7 (pad rows
// 100..111 compute garbage that never escapes: gathers/pool only touch n<100).
template <int F>
__device__ __forceinline__ void cheb_layer(
    float* __restrict__ A, float* __restrict__ T1, float* __restrict__ T2,
    const unsigned short* __restrict__ csr_src,
    const int* __restrict__ csr_off,
    const float* __restrict__ sdinv,
    const float* __restrict__ W, const float* __restrict__ bias,
    int tid)
{
    const int cq4 = (tid & 15) * 4;
    const int n0  = (tid >> 4) * 7;

    float4 acc[7];
    const float4 bv = *(const float4*)&bias[cq4];
#pragma unroll
    for (int i = 0; i < 7; i++) acc[i] = bv;

    for (int cb = 0; cb < F; cb += 8) {
        prop8(A, ASTR, cb, T1, (const float*)0, 0, 0, csr_src, csr_off, sdinv, tid);
        __syncthreads();
        prop8(T1, TSTR, 0, T2, A, cb, 1, csr_src, csr_off, sdinv, tid);
        __syncthreads();

        // partial matmul over this 8-feature slice, 3 sections (X0, X1, X2)
        for (int sec = 0; sec < 3; sec++) {
            const float* xp; int xstr, xoff, wrow0;
            if (sec == 0)      { xp = A;  xstr = ASTR; xoff = cb; wrow0 = cb; }
            else if (sec == 1) { xp = T1; xstr = TSTR; xoff = 0;  wrow0 = F + cb; }
            else               { xp = T2; xstr = TSTR; xoff = 0;  wrow0 = 2 * F + cb; }
            for (int j4 = 0; j4 < 8; j4 += 4) {
                const float4 w0 = *(const float4*)&W[(wrow0 + j4 + 0) * HID + cq4];
                const float4 w1 = *(const float4*)&W[(wrow0 + j4 + 1) * HID + cq4];
                const float4 w2 = *(const float4*)&W[(wrow0 + j4 + 2) * HID + cq4];
                const float4 w3 = *(const float4*)&W[(wrow0 + j4 + 3) * HID + cq4];
                const float* xb = xp + n0 * xstr + xoff + j4;
#pragma unroll
                for (int i = 0; i < 7; i++) {
                    const float4 x = *(const float4*)&xb[i * xstr];
                    fma4(acc[i], x.x, w0); fma4(acc[i], x.y, w1);
                    fma4(acc[i], x.z, w2); fma4(acc[i], x.w, w3);
                }
            }
        }
        __syncthreads();   // T1/T2 (and A-slice) reads done before next overwrite
    }

    // H = relu(acc) -> A (pad rows written with don't-care values; no guard)
#pragma unroll
    for (int i = 0; i < 7; i++) {
        float4 o;
        o.x = fmaxf(acc[i].x, 0.f); o.y = fmaxf(acc[i].y, 0.f);
        o.z = fmaxf(acc[i].z, 0.f); o.w = fmaxf(acc[i].w, 0.f);
        *(float4*)&A[(n0 + i) * ASTR + cq4] = o;
    }
    __syncthreads();
}

__global__ __launch_bounds__(256, 4) void gnn_kernel(
    const float* __restrict__ feat,
    const int* __restrict__ src, const int* __restrict__ dst,
    const float* __restrict__ W1, const float* __restrict__ b1,
    const float* __restrict__ W2, const float* __restrict__ b2,
    const float* __restrict__ W3, const float* __restrict__ b3,
    const float* __restrict__ Wfc, const float* __restrict__ bfc,
    float* __restrict__ out)
{
    __shared__ __align__(16) float A[NPAD * ASTR];
    __shared__ __align__(16) float T1[NPAD * TSTR];
    __shared__ __align__(16) float T2[NPAD * TSTR];
    __shared__ unsigned short csr_src[EPG];
    __shared__ int   csr_off[P + 1];
    __shared__ float sdinv[P];

    const int g = blockIdx.x;
    const int tid = threadIdx.x;
    const int base = g * P;
    const int* srcg = src + g * EPG;
    const int* dstg = dst + g * EPG;

    int* deg = (int*)T1;   // aliased; consumed before layer 1
    int* cur = (int*)T2;   // aliased; consumed before layer 1

    // ---- degree count + feat load ----
    for (int i = tid; i < P; i += 256) deg[i] = 0;
    __syncthreads();
    for (int e = tid; e < EPG; e += 256) {
        int d = dstg[e] - base;
        atomicAdd(&deg[d], 1);
    }
    for (int i = tid; i < P * INF / 4; i += 256) {
        int n = i >> 2, fq = (i & 3) * 4;
        *(float4*)&A[n * ASTR + fq] = *(const float4*)&feat[(size_t)base * INF + i * 4];
    }
    __syncthreads();

    for (int i = tid; i < P; i += 256) {
        int dg = deg[i] > 1 ? deg[i] : 1;
        sdinv[i] = rsqrtf((float)dg);
    }
    // ---- prefix scan of degrees: serial by thread 0 (P=100, negligible) ----
    if (tid == 0) {
        int run = 0;
        csr_off[0] = 0;
        for (int i = 0; i < P; i++) { run += deg[i]; csr_off[i + 1] = run; }
    }
    __syncthreads();
    for (int i = tid; i < P; i += 256) cur[i] = csr_off[i];
    __syncthreads();
    // ---- CSR fill ----
    for (int e = tid; e < EPG; e += 256) {
        int s = srcg[e] - base;
        int d = dstg[e] - base;
        int pos = atomicAdd(&cur[d], 1);
        csr_src[pos] = (unsigned short)s;
    }
    __syncthreads();

    // ---- 3 ChebConv layers ----
    cheb_layer<INF>(A, T1, T2, csr_src, csr_off, sdinv, W1, b1, tid);
    cheb_layer<HID>(A, T1, T2, csr_src, csr_off, sdinv, W2, b2, tid);
    cheb_layer<HID>(A, T1, T2, csr_src, csr_off, sdinv, W3, b3, tid);

    // ---- mean pool + FC (T1 as scratch: 320 floats <= 896) ----
    {
        const int lane = tid & 63, w = tid >> 6;
        float s = 0.f;
        for (int n = w; n < P; n += 4) s += A[n * ASTR + lane];
        T1[w * 64 + lane] = s;
    }
    __syncthreads();
    if (tid < HID) {
        float hg = (T1[tid] + T1[64 + tid] + T1[128 + tid] + T1[192 + tid]) * (1.0f / P);
        T1[256 + tid] = hg;
    }
    __syncthreads();
    if (tid < NOUT) {
        float o = bfc[tid];
        for (int c = 0; c < HID; c++) o += T1[256 + c] * Wfc[c * NOUT + tid];
        out[g * NOUT + tid] = o;
    }
}

extern "C" void kernel_launch(void* const* d_in, const int* in_sizes, int n_in,
                              void* d_out, int out_size, void* d_ws, size_t ws_size,
                              hipStream_t stream)
{
    const float* feat = (const float*)d_in[0];
    const int*   src  = (const int*)d_in[1];
    const int*   dst  = (const int*)d_in[2];
    const float* W1  = (const float*)d_in[5];
    const float* b1  = (const float*)d_in[6];
    const float* W2  = (const float*)d_in[7];
    const float* b2  = (const float*)d_in[8];
    const float* W3  = (const float*)d_in[9];
    const float* b3  = (const float*)d_in[10];
    const float* Wfc = (const float*)d_in[11];
    const float* bfc = (const float*)d_in[12];
    float* out = (float*)d_out;

    gnn_kernel<<<NGRAPH, 256, 0, stream>>>(feat, src, dst,
                                           W1, b1, W2, b2, W3, b3, Wfc, bfc, out);
}

// Round 12
// 239.466 us; speedup vs baseline: 3.1614x; 1.1588x over previous
//
#include <hip/hip_runtime.h>

#define NGRAPH 1000
#define P      100
#define EPG    1200
#define INF    16
#define HID    64
#define NOUT   5

#define ASTR   68    // A row stride (17 granules, odd -> conflict-free matmul reads)
#define TSTR   8     // T1/T2 row stride = slice width
#define NPAD   112   // 16 uniform groups * 7 nodes (rows 100..111 = don't-care pad)

// LDS: A 112*68*4=30464 + T1/T2 2*112*8*4=7168 + csr_src 2400 + csr_off 404
//      + dinv 448 = 40,884 B -> 4 blocks/CU.  deg/cursor alias T1/T2.
//
// PRESCALED-ACTIVATION FORM (r12): all stored activations are Y = dinv * X.
//   gather:  sum_e Y[s]                      (NO per-edge weight load/mul)
//   X1-type: Y1 = -dinv[n]^2 * sum
//   X2-type: Y2 = -2*dinv[n]^2 * sum - Y0[n]
//   matmul:  X_k[n,:] = sdeg[n]*Y_k[n,:] for all k -> row scale folds into
//   epilogue: layers 1,2: A = relu(acc + dinv[n]*bias)   ( = dinv*H )
//             layer 3   : A = relu(acc/dinv[n] + bias)   ( = H, pool unchanged )
//
// HARD RULES (r6/r7/r9/r10/r11 lessons):
//  - every loop touching acc[] is #pragma unroll, compile-time trip, no guards
//  - allocator pins 64 VGPRs and spills above it; keep peak pressure < 64
//  - do NOT hand-unroll the gather edge loop (r11: -16% — it defeats the
//    compiler's own scheduling of the simple loop)

__device__ __forceinline__ void fma4(float4& a, float s, const float4 w) {
    a.x += s * w.x; a.y += s * w.y; a.z += s * w.z; a.w += s * w.w;
}

// Gather one 8-column slice D[n][0..8) (n < P) from CSR, prescaled form.
// isX2=0: D = -dinv[n]^2 * sum_e S[s]
// isX2=1: D = -2*dinv[n]^2 * sum_e S[s] - A0[n*ASTR + aoff]
__device__ __forceinline__ void prop8(
    const float* __restrict__ S, int sstride, int soff,
    float* __restrict__ D,
    const float* __restrict__ A0, int aoff, int isX2,
    const unsigned short* __restrict__ csr_src,
    const int* __restrict__ csr_off,
    const float* __restrict__ dinv,
    int tid)
{
    const int q = tid & 1;        // feature quad within slice
    const int n = tid >> 1;       // node (128 slots >= 100)
    if (n < P) {
        const int kb = csr_off[n], ke = csr_off[n + 1];
        float ax = 0.f, ay = 0.f, az = 0.f, aw = 0.f;
        for (int k = kb; k < ke; k++) {
            int s = csr_src[k];
            const float4 x = *(const float4*)&S[s * sstride + soff + q * 4];
            ax += x.x; ay += x.y; az += x.z; aw += x.w;
        }
        float dn = dinv[n];
        float d2 = dn * dn;
        float4 o;
        if (!isX2) {
            float m = -d2;
            o.x = m * ax; o.y = m * ay; o.z = m * az; o.w = m * aw;
        } else {
            float m = -2.f * d2;
            const float4 y0 = *(const float4*)&A0[n * ASTR + aoff + q * 4];
            o.x = m * ax - y0.x; o.y = m * ay - y0.y;
            o.z = m * az - y0.z; o.w = m * aw - y0.w;
        }
        *(float4*)&D[n * TSTR + q * 4] = o;
    }
}

// One ChebConv(K=3) layer in prescaled form: A (Y, F cols) -> A (Y or H).
// Thread: cq4=(tid&15)*4 output cols; 7 uniform nodes n0=(tid>>4)*7 (pad rows
// 100..111 compute garbage that never escapes: gathers/pool only touch n<100).
template <int F, int FINAL>
__device__ __forceinline__ void cheb_layer(
    float* __restrict__ A, float* __restrict__ T1, float* __restrict__ T2,
    const unsigned short* __restrict__ csr_src,
    const int* __restrict__ csr_off,
    const float* __restrict__ dinv,
    const float* __restrict__ W, const float* __restrict__ bias,
    int tid)
{
    const int cq4 = (tid & 15) * 4;
    const int n0  = (tid >> 4) * 7;

    float4 acc[7];
#pragma unroll
    for (int i = 0; i < 7; i++) acc[i] = make_float4(0.f, 0.f, 0.f, 0.f);

    for (int cb = 0; cb < F; cb += 8) {
        prop8(A, ASTR, cb, T1, (const float*)0, 0, 0, csr_src, csr_off, dinv, tid);
        __syncthreads();
        prop8(T1, TSTR, 0, T2, A, cb, 1, csr_src, csr_off, dinv, tid);
        __syncthreads();

        // partial matmul over this 8-feature slice, 3 sections (Y0, Y1, Y2)
        for (int sec = 0; sec < 3; sec++) {
            const float* xp; int xstr, xoff, wrow0;
            if (sec == 0)      { xp = A;  xstr = ASTR; xoff = cb; wrow0 = cb; }
            else if (sec == 1) { xp = T1; xstr = TSTR; xoff = 0;  wrow0 = F + cb; }
            else               { xp = T2; xstr = TSTR; xoff = 0;  wrow0 = 2 * F + cb; }
            for (int j4 = 0; j4 < 8; j4 += 4) {
                const float4 w0 = *(const float4*)&W[(wrow0 + j4 + 0) * HID + cq4];
                const float4 w1 = *(const float4*)&W[(wrow0 + j4 + 1) * HID + cq4];
                const float4 w2 = *(const float4*)&W[(wrow0 + j4 + 2) * HID + cq4];
                const float4 w3 = *(const float4*)&W[(wrow0 + j4 + 3) * HID + cq4];
                const float* xb = xp + n0 * xstr + xoff + j4;
#pragma unroll
                for (int i = 0; i < 7; i++) {
                    const float4 x = *(const float4*)&xb[i * xstr];
                    fma4(acc[i], x.x, w0); fma4(acc[i], x.y, w1);
                    fma4(acc[i], x.z, w2); fma4(acc[i], x.w, w3);
                }
            }
        }
        __syncthreads();   // T1/T2 (and A-slice) reads done before next overwrite
    }

    // Epilogue (pad rows get don't-care values; no guard):
    //  FINAL=0: A = relu(acc + dinv[n]*b)   (stores Y = dinv*H)
    //  FINAL=1: A = relu(acc/dinv[n] + b)   (stores H; pool reads H directly)
    const float4 bv = *(const float4*)&bias[cq4];
#pragma unroll
    for (int i = 0; i < 7; i++) {
        float dn = dinv[n0 + i];
        float4 o;
        if (FINAL) {
            float sd = 1.0f / dn;
            o.x = fmaxf(acc[i].x * sd + bv.x, 0.f);
            o.y = fmaxf(acc[i].y * sd + bv.y, 0.f);
            o.z = fmaxf(acc[i].z * sd + bv.z, 0.f);
            o.w = fmaxf(acc[i].w * sd + bv.w, 0.f);
        } else {
            o.x = fmaxf(acc[i].x + bv.x * dn, 0.f);
            o.y = fmaxf(acc[i].y + bv.y * dn, 0.f);
            o.z = fmaxf(acc[i].z + bv.z * dn, 0.f);
            o.w = fmaxf(acc[i].w + bv.w * dn, 0.f);
        }
        *(float4*)&A[(n0 + i) * ASTR + cq4] = o;
    }
    __syncthreads();
}

__global__ __launch_bounds__(256, 4) void gnn_kernel(
    const float* __restrict__ feat,
    const int* __restrict__ src, const int* __restrict__ dst,
    const float* __restrict__ W1, const float* __restrict__ b1,
    const float* __restrict__ W2, const float* __restrict__ b2,
    const float* __restrict__ W3, const float* __restrict__ b3,
    const float* __restrict__ Wfc, const float* __restrict__ bfc,
    float* __restrict__ out)
{
    __shared__ __align__(16) float A[NPAD * ASTR];
    __shared__ __align__(16) float T1[NPAD * TSTR];
    __shared__ __align__(16) float T2[NPAD * TSTR];
    __shared__ unsigned short csr_src[EPG];
    __shared__ int   csr_off[P + 1];
    __shared__ float dinv[NPAD];   // rows 100..111 = 1.0 (keeps pad rows finite)

    const int g = blockIdx.x;
    const int tid = threadIdx.x;
    const int base = g * P;
    const int* srcg = src + g * EPG;
    const int* dstg = dst + g * EPG;

    int* deg = (int*)T1;   // aliased; consumed before layer 1
    int* cur = (int*)T2;   // aliased; consumed before layer 1

    // ---- degree count ----
    for (int i = tid; i < P; i += 256) deg[i] = 0;
    __syncthreads();
    for (int e = tid; e < EPG; e += 256) {
        int d = dstg[e] - base;
        atomicAdd(&deg[d], 1);
    }
    __syncthreads();

    // ---- dinv + serial prefix scan (both read deg) ----
    for (int i = tid; i < NPAD; i += 256) {
        if (i < P) {
            int dg = deg[i] > 1 ? deg[i] : 1;
            dinv[i] = rsqrtf((float)dg);
        } else {
            dinv[i] = 1.0f;
        }
    }
    if (tid == 0) {
        int run = 0;
        csr_off[0] = 0;
        for (int i = 0; i < P; i++) { run += deg[i]; csr_off[i + 1] = run; }
    }
    __syncthreads();

    // ---- feat load prescaled (A = dinv*feat) + CSR cursor init ----
    for (int i = tid; i < P * INF / 4; i += 256) {
        int n = i >> 2, fq = (i & 3) * 4;
        float4 v = *(const float4*)&feat[(size_t)base * INF + i * 4];
        float dn = dinv[n];
        v.x *= dn; v.y *= dn; v.z *= dn; v.w *= dn;
        *(float4*)&A[n * ASTR + fq] = v;
    }
    for (int i = tid; i < P; i += 256) cur[i] = csr_off[i];
    __syncthreads();
    // ---- CSR fill ----
    for (int e = tid; e < EPG; e += 256) {
        int s = srcg[e] - base;
        int d = dstg[e] - base;
        int pos = atomicAdd(&cur[d], 1);
        csr_src[pos] = (unsigned short)s;
    }
    __syncthreads();

    // ---- 3 ChebConv layers (prescaled; final layer emits H) ----
    cheb_layer<INF, 0>(A, T1, T2, csr_src, csr_off, dinv, W1, b1, tid);
    cheb_layer<HID, 0>(A, T1, T2, csr_src, csr_off, dinv, W2, b2, tid);
    cheb_layer<HID, 1>(A, T1, T2, csr_src, csr_off, dinv, W3, b3, tid);

    // ---- mean pool + FC (T1 as scratch: 320 floats <= 896) ----
    {
        const int lane = tid & 63, w = tid >> 6;
        float s = 0.f;
        for (int n = w; n < P; n += 4) s += A[n * ASTR + lane];
        T1[w * 64 + lane] = s;
    }
    __syncthreads();
    if (tid < HID) {
        float hg = (T1[tid] + T1[64 + tid] + T1[128 + tid] + T1[192 + tid]) * (1.0f / P);
        T1[256 + tid] = hg;
    }
    __syncthreads();
    if (tid < NOUT) {
        float o = bfc[tid];
        for (int c = 0; c < HID; c++) o += T1[256 + c] * Wfc[c * NOUT + tid];
        out[g * NOUT + tid] = o;
    }
}

extern "C" void kernel_launch(void* const* d_in, const int* in_sizes, int n_in,
                              void* d_out, int out_size, void* d_ws, size_t ws_size,
                              hipStream_t stream)
{
    const float* feat = (const float*)d_in[0];
    const int*   src  = (const int*)d_in[1];
    const int*   dst  = (const int*)d_in[2];
    const float* W1  = (const float*)d_in[5];
    const float* b1  = (const float*)d_in[6];
    const float* W2  = (const float*)d_in[7];
    const float* b2  = (const float*)d_in[8];
    const float* W3  = (const float*)d_in[9];
    const float* b3  = (const float*)d_in[10];
    const float* Wfc = (const float*)d_in[11];
    const float* bfc = (const float*)d_in[12];
    float* out = (float*)d_out;

    gnn_kernel<<<NGRAPH, 256, 0, stream>>>(feat, src, dst,
                                           W1, b1, W2, b2, W3, b3, Wfc, bfc, out);
}